// Round 5
// baseline (255.423 us; speedup 1.0000x reference)
//
#include <hip/hip_runtime.h>
#include <hip/hip_fp16.h>

namespace {

constexpr int kB = 128, kI = 1152, kD = 8, kN = 32, kE = 16;
constexpr int kTI = 4;                 // input capsules per chunk
constexpr int kNC = kI / kTI;          // 288 chunks
constexpr int kCG = 4;                 // chunk groups for 2-level reduce
constexpr int kCPG = kNC / kCG;        // 72 chunks per group

constexpr size_t kPartBytes  = (size_t)kNC * kB * kN * kE * 2;   // 36.9 MB fp16
constexpr size_t kPart2Bytes = (size_t)kCG * kB * kN * kE * 4;   // 1 MB f32
constexpr size_t kVsumBytes  = (size_t)kB * kN * kE * 4;         // 256 KB f32

typedef _Float16 h2v __attribute__((ext_vector_type(2)));

__device__ __forceinline__ float fdot2(__half2 a, __half2 b, float c) {
#if defined(__has_builtin) && __has_builtin(__builtin_amdgcn_fdot2)
  return __builtin_amdgcn_fdot2(__builtin_bit_cast(h2v, a),
                                __builtin_bit_cast(h2v, b), c, false);
#else
  float2 af = __half22float2(a), bf = __half22float2(b);
  return fmaf(af.y, bf.y, fmaf(af.x, bf.x, c));
#endif
}

union I4H { int4 v; __half2 h[4]; };

// Routing pass. Lanes = (eh, n): eh = e-octet (2), n = out-capsule (32).
// W chunk (4 i) loaded global->VGPR directly in lane order (128 half2 regs,
// nothing in LDS to rematerialize from). Each of 4 waves handles 8 batches.
template<int PASS>
__global__ __launch_bounds__(256, 2)
void caps_pass(const float* __restrict__ x, const float* __restrict__ W,
               const float* __restrict__ bias, const __half* __restrict__ vsh,
               __half* __restrict__ part)
{
  __shared__ __half2 xlds[32][kTI * kD];   // dup half2 per (b-local, i*8+d), 4 KB

  const int chunk = (int)blockIdx.x;
  const int i0 = chunk * kTI;
  const int b0 = (int)blockIdx.y * 32;
  const int t = (int)threadIdx.x;
  const int lane = t & 63;
  const int wv = t >> 6;
  const int eh = lane >> 5;   // e-octet
  const int n  = lane & 31;   // out capsule

  // ---- stage x tile: 32 b x (4 i x 8 d), duplicated half2 (once, 4 KB) ----
  {
    const int r = t >> 3, c = (t & 7) * 4;
    const float4 f4 = *reinterpret_cast<const float4*>(
        x + (size_t)(b0 + r) * (kI * kD) + (size_t)i0 * kD + c);
    xlds[r][c + 0] = __half2half2(__float2half_rn(f4.x));
    xlds[r][c + 1] = __half2half2(__float2half_rn(f4.y));
    xlds[r][c + 2] = __half2half2(__float2half_rn(f4.z));
    xlds[r][c + 3] = __half2half2(__float2half_rn(f4.w));
  }

  // ---- W chunk global -> registers, lane order. 64x dwordx4, each wave-inst
  // covers 32 full 64B lines (W[i][n][d][:] is exactly one line). ----
  __half2 wr[kTI][kD][4];
  {
    const float* wb = W + ((size_t)i0 * kN + n) * (kD * kE) + eh * 8;
#pragma unroll
    for (int i = 0; i < kTI; ++i)
#pragma unroll
      for (int d = 0; d < kD; ++d) {
        const float4* p = reinterpret_cast<const float4*>(
            wb + (size_t)i * (kN * kD * kE) + d * kE);
        float4 a = p[0], b4 = p[1];
        wr[i][d][0] = __floats2half2_rn(a.x, a.y);
        wr[i][d][1] = __floats2half2_rn(a.z, a.w);
        wr[i][d][2] = __floats2half2_rn(b4.x, b4.y);
        wr[i][d][3] = __floats2half2_rn(b4.z, b4.w);
      }
  }

  float bf[kTI];
#pragma unroll
  for (int i = 0; i < kTI; ++i) bf[i] = bias[(size_t)(i0 + i) * kN + n];

  // PASS 0: coupling c depends only on (i, n) -> softmax once, outside b-loop
  __half2 c0[kTI];
  if (PASS == 0) {
#pragma unroll
    for (int i = 0; i < kTI; ++i) {
      float lg = bf[i];
      float m = lg;
#pragma unroll
      for (int o = 1; o <= 16; o <<= 1) m = fmaxf(m, __shfl_xor(m, o, 64));
      float ev = __expf(lg - m);
      float sm = ev;
#pragma unroll
      for (int o = 1; o <= 16; o <<= 1) sm += __shfl_xor(sm, o, 64);
      c0[i] = __half2half2(__float2half_rn(ev / sm));
    }
  }

  __syncthreads();

#pragma unroll 2
  for (int bb = 0; bb < 8; ++bb) {
    const int bl = wv * 8 + bb;
    const int b = b0 + bl;
    I4H vq;
    if (PASS > 0)
      vq.v = *reinterpret_cast<const int4*>(vsh + ((size_t)b * kN + n) * kE + eh * 8);

    __half2 s[4];
#pragma unroll
    for (int k = 0; k < 4; ++k) s[k] = __half2half2(__float2half(0.f));

#pragma unroll
    for (int i = 0; i < kTI; ++i) {
      I4H xa, xb;
      xa.v = *reinterpret_cast<const int4*>(&xlds[bl][i * kD]);
      xb.v = *reinterpret_cast<const int4*>(&xlds[bl][i * kD + 4]);
      __half2 uh[4];
#pragma unroll
      for (int k = 0; k < 4; ++k) uh[k] = __hmul2(xa.h[0], wr[i][0][k]);
#pragma unroll
      for (int d = 1; d < 4; ++d)
#pragma unroll
        for (int k = 0; k < 4; ++k) uh[k] = __hfma2(xa.h[d], wr[i][d][k], uh[k]);
#pragma unroll
      for (int d = 0; d < 4; ++d)
#pragma unroll
        for (int k = 0; k < 4; ++k) uh[k] = __hfma2(xb.h[d], wr[i][4 + d][k], uh[k]);

      __half2 c2;
      if (PASS == 0) {
        c2 = c0[i];
      } else {
        float lg = bf[i];
#pragma unroll
        for (int k = 0; k < 4; ++k) lg = fdot2(uh[k], vq.h[k], lg);
        lg += __shfl_xor(lg, 32, 64);           // sum both e-octets
        float m = lg;
#pragma unroll
        for (int o = 1; o <= 16; o <<= 1) m = fmaxf(m, __shfl_xor(m, o, 64));
        float ev = __expf(lg - m);
        float sm = ev;
#pragma unroll
        for (int o = 1; o <= 16; o <<= 1) sm += __shfl_xor(sm, o, 64);
        c2 = __half2half2(__float2half_rn(ev / sm));
      }
#pragma unroll
      for (int k = 0; k < 4; ++k) s[k] = __hfma2(c2, uh[k], s[k]);
    }
    I4H o;
#pragma unroll
    for (int k = 0; k < 4; ++k) o.h[k] = s[k];
    // part[ch][b][n][e]: per wave-inst 1 KB contiguous
    *reinterpret_cast<int4*>(
        part + (((size_t)chunk * kB + b) * kN + n) * kE + eh * 8) = o.v;
  }
}

// Level-1 reduce: sum 72 chunks of fp16 partials -> f32 partial2[cg][b][n][e].
// int4-wide reads: 1 KB per wave-instruction.
__global__ __launch_bounds__(256)
void caps_reduce1(const __half* __restrict__ part, float* __restrict__ partial2)
{
  const int cg = (int)blockIdx.y;
  const int t = (int)threadIdx.x;
  const int b = (int)blockIdx.x * 4 + (t >> 6);
  const int l = t & 63;                      // int4 slot: halves l*8 .. l*8+7
  const __half* p0 = part + ((size_t)(cg * kCPG) * kB + b) * (kN * kE) + l * 8;
  constexpr size_t chStride = (size_t)kB * kN * kE;   // halves per chunk
  float acc[8] = {0.f, 0.f, 0.f, 0.f, 0.f, 0.f, 0.f, 0.f};
#pragma unroll 4
  for (int ch = 0; ch < kCPG; ++ch) {
    I4H q; q.v = *reinterpret_cast<const int4*>(p0 + (size_t)ch * chStride);
#pragma unroll
    for (int k = 0; k < 4; ++k) {
      float2 f = __half22float2(q.h[k]);
      acc[2 * k] += f.x; acc[2 * k + 1] += f.y;
    }
  }
  float* dst = partial2 + ((size_t)cg * kB + b) * (kN * kE) + l * 8;
  *reinterpret_cast<float4*>(dst)     = make_float4(acc[0], acc[1], acc[2], acc[3]);
  *reinterpret_cast<float4*>(dst + 4) = make_float4(acc[4], acc[5], acc[6], acc[7]);
}

// Final: sum 4 chunk-groups, squash. MODE 0: vsum=v,vsh=v; 1: vsum+=v; 2: out=v.
template<int MODE>
__global__ __launch_bounds__(256)
void caps_final(const float* __restrict__ partial2, float* __restrict__ vsum,
                __half* __restrict__ vsh, float* __restrict__ out)
{
  const int b = (int)blockIdx.x;
  const int t = (int)threadIdx.x;
  const int nl = t >> 3, ep = t & 7;
  const size_t o = ((size_t)b * kN + nl) * kE + ep * 2;
  float ax = 0.f, ay = 0.f;
#pragma unroll
  for (int cg = 0; cg < kCG; ++cg) {
    float2 f = *reinterpret_cast<const float2*>(
        partial2 + (size_t)cg * kB * kN * kE + o);
    ax += f.x; ay += f.y;
  }
  float s2 = ax * ax + ay * ay;
  s2 += __shfl_xor(s2, 1, 64);
  s2 += __shfl_xor(s2, 2, 64);
  s2 += __shfl_xor(s2, 4, 64);
  const float sc = (s2 / (1.f + s2)) * rsqrtf(fmaxf(s2, 1e-30f));
  float vx = ax * sc, vy = ay * sc;
  if (MODE == 2) {
    *reinterpret_cast<float2*>(out + o) = make_float2(vx, vy);
  } else {
    if (MODE == 1) {
      float2 old = *reinterpret_cast<const float2*>(vsum + o);
      vx += old.x; vy += old.y;
    }
    *reinterpret_cast<float2*>(vsum + o) = make_float2(vx, vy);
    *reinterpret_cast<__half2*>(vsh + o) = __floats2half2_rn(vx, vy);
  }
}

}  // namespace

extern "C" void kernel_launch(void* const* d_in, const int* in_sizes, int n_in,
                              void* d_out, int out_size, void* d_ws, size_t ws_size,
                              hipStream_t stream) {
  (void)in_sizes; (void)n_in; (void)out_size; (void)ws_size;
  const float* x    = reinterpret_cast<const float*>(d_in[0]);
  const float* W    = reinterpret_cast<const float*>(d_in[1]);
  const float* bias = reinterpret_cast<const float*>(d_in[2]);
  float* out = reinterpret_cast<float*>(d_out);

  char* ws = reinterpret_cast<char*>(d_ws);
  __half* part     = reinterpret_cast<__half*>(ws);
  float*  partial2 = reinterpret_cast<float*>(ws + kPartBytes);
  float*  vsum     = reinterpret_cast<float*>(ws + kPartBytes + kPart2Bytes);
  __half* vsh      = reinterpret_cast<__half*>(ws + kPartBytes + kPart2Bytes + kVsumBytes);

  dim3 pg(kNC, kB / 32), pb(256);
  dim3 rg(kB / 4, kCG), rb(256);

  // iter 0: c = softmax(bias); v0 -> vsum/vsh
  caps_pass<0><<<pg, pb, 0, stream>>>(x, W, bias, vsh, part);
  caps_reduce1<<<rg, rb, 0, stream>>>(part, partial2);
  caps_final<0><<<kB, 256, 0, stream>>>(partial2, vsum, vsh, out);
  // iter 1: logits = bias + <u_hat, v0>; vsum += v1
  caps_pass<1><<<pg, pb, 0, stream>>>(x, W, bias, vsh, part);
  caps_reduce1<<<rg, rb, 0, stream>>>(part, partial2);
  caps_final<1><<<kB, 256, 0, stream>>>(partial2, vsum, vsh, out);
  // iter 2: logits = bias + <u_hat, v0+v1>; out = squash(s)
  caps_pass<2><<<pg, pb, 0, stream>>>(x, W, bias, vsh, part);
  caps_reduce1<<<rg, rb, 0, stream>>>(part, partial2);
  caps_final<2><<<kB, 256, 0, stream>>>(partial2, vsum, vsh, out);
}